// Round 1
// baseline (501.064 us; speedup 1.0000x reference)
//
#include <hip/hip_runtime.h>
#include <cstdint>
#include <cstddef>

// PerceiverAttention on MI355X (gfx950).
// Pipeline: wtrans x3 -> ln -> gemm<KV> -> gemm<Q> -> attn -> combine -> gemm<OUT>
// All matmuls: bf16 MFMA 32x32x16, fp32 accum. 128x128 tile, BK=64,
// global_load_lds width=16, XOR-swizzled LDS (conflict-minimal ds_read_b128).

typedef unsigned short u16;
typedef __bf16 bf16x8 __attribute__((ext_vector_type(8)));
typedef float f32x16 __attribute__((ext_vector_type(16)));

#define MFMA32(a, b, c) __builtin_amdgcn_mfma_f32_32x32x16_bf16((a), (b), (c), 0, 0, 0)

__device__ __forceinline__ u16 f2bf(float f) {  // RNE float->bf16
  unsigned u = __builtin_bit_cast(unsigned, f);
  u += 0x7FFFu + ((u >> 16) & 1u);
  return (u16)(u >> 16);
}

__device__ __forceinline__ f32x16 zero16() {
  f32x16 z;
#pragma unroll
  for (int i = 0; i < 16; ++i) z[i] = 0.f;
  return z;
}

#if defined(__has_builtin)
#if __has_builtin(__builtin_amdgcn_global_load_lds)
#define HAVE_GLDS 1
#endif
#endif

// Async global->LDS, 16 B/lane. HW writes lane i's data at lbase + i*16
// (wave-uniform base, lane-linear dest) - lbase must NOT include lane offset.
__device__ __forceinline__ void async16(const u16* g, u16* lbase, int lane) {
#ifdef HAVE_GLDS
  typedef const __attribute__((address_space(1))) void* gp_t;
  typedef __attribute__((address_space(3))) void* lp_t;
  __builtin_amdgcn_global_load_lds((gp_t)g, (lp_t)lbase, 16, 0, 0);
#else
  *(uint4*)(lbase + lane * 8) = *(const uint4*)g;
#endif
}

// ---------------- weight transpose fp32 -> bf16, Wt[n][k] = W[k][n] -----------
__global__ void wtrans(const float* __restrict__ W, u16* __restrict__ Wt, int K, int N) {
  __shared__ float t[32][33];
  int n0 = blockIdx.x * 32, k0 = blockIdx.y * 32;
  int tx = threadIdx.x, ty = threadIdx.y;  // 32 x 8
#pragma unroll
  for (int i = 0; i < 4; ++i)
    t[ty + 8 * i][tx] = W[(size_t)(k0 + ty + 8 * i) * N + n0 + tx];
  __syncthreads();
#pragma unroll
  for (int i = 0; i < 4; ++i)
    Wt[(size_t)(n0 + ty + 8 * i) * K + k0 + tx] = f2bf(t[tx][ty + 8 * i]);
}

// ---------------- LayerNorm of x and latents -> bf16 ------------------------
// rows 0..32767: x rows -> kvin[b*4160 + pos]
// rows 32768..33279: latent rows -> kvin[b*4160 + 4096 + j] AND qin[row]
__global__ void ln_kernel(const float* __restrict__ x, const float* __restrict__ lat,
                          const float* __restrict__ g1, const float* __restrict__ b1,
                          const float* __restrict__ g2, const float* __restrict__ b2,
                          u16* __restrict__ kvin, u16* __restrict__ qin) {
  int row = blockIdx.x;
  const float *src, *g, *bb;
  u16 *dst, *dst2 = nullptr;
  if (row < 32768) {
    int b = row >> 12, pos = row & 4095;
    src = x + (size_t)row * 1024;
    dst = kvin + (size_t)(b * 4160 + pos) * 1024;
    g = g1; bb = b1;
  } else {
    int i = row - 32768;
    int b = i >> 6, j = i & 63;
    src = lat + (size_t)i * 1024;
    dst = kvin + (size_t)(b * 4160 + 4096 + j) * 1024;
    dst2 = qin + (size_t)i * 1024;
    g = g2; bb = b2;
  }
  int t = threadIdx.x;
  float4 v = *(const float4*)(src + t * 4);
  float s = v.x + v.y + v.z + v.w;
  float ss = v.x * v.x + v.y * v.y + v.z * v.z + v.w * v.w;
#pragma unroll
  for (int off = 32; off; off >>= 1) {
    s += __shfl_xor(s, off);
    ss += __shfl_xor(ss, off);
  }
  __shared__ float red[8];
  int w = t >> 6;
  if ((t & 63) == 0) { red[w] = s; red[w + 4] = ss; }
  __syncthreads();
  s = red[0] + red[1] + red[2] + red[3];
  ss = red[4] + red[5] + red[6] + red[7];
  float mu = s * (1.f / 1024.f);
  float var = ss * (1.f / 1024.f) - mu * mu;
  float rstd = rsqrtf(var + 1e-5f);
  float4 gv = *(const float4*)(g + t * 4);
  float4 bv = *(const float4*)(bb + t * 4);
  ushort4 o;
  o.x = f2bf((v.x - mu) * rstd * gv.x + bv.x);
  o.y = f2bf((v.y - mu) * rstd * gv.y + bv.y);
  o.z = f2bf((v.z - mu) * rstd * gv.z + bv.z);
  o.w = f2bf((v.w - mu) * rstd * gv.w + bv.w);
  *(ushort4*)(dst + t * 4) = o;
  if (dst2) *(ushort4*)(dst2 + t * 4) = o;
}

// ---------------- 128x128 bf16 GEMM: C[m][n] = sum_k A[m][k]*Bt[n][k] --------
// EPI 0: KV proj. nb<8 -> K scatter (b,h,key,d); nb>=8 -> V^T via LDS transpose.
// EPI 1: Q proj  -> (b,h,q,d) scaled by 1/8 (folds qk scale^2).
// EPI 2: out proj -> fp32 row-major direct to d_out.
template <int EPI>
__global__ void __launch_bounds__(256, 2) gemm128(
    const u16* __restrict__ A, const u16* __restrict__ Bt, int K,
    u16* __restrict__ oK, u16* __restrict__ oV, float* __restrict__ oF) {
  __shared__ __align__(16) u16 lds[18432];  // As 8192 | Bs 8192; epilogue reuses as T[128][144]
  u16* As = lds;
  u16* Bs = lds + 8192;
  const int tid = threadIdx.x;
  const int lane = tid & 63;
  const int w = tid >> 6;
  const int lc = lane & 31;
  const int hh = lane >> 5;
  const int m0 = blockIdx.y * 128;
  const int n0 = blockIdx.x * 128;
  const int wm = (w >> 1) * 64;
  const int wn = (w & 1) * 64;

  f32x16 acc[2][2];
#pragma unroll
  for (int i = 0; i < 2; ++i)
#pragma unroll
    for (int j = 0; j < 2; ++j) acc[i][j] = zero16();

  const int rsub = lane >> 3;   // 0..7 : sub-row within a wave's 8-row chunk
  const int cslot = lane & 7;   // 0..7 : 16B slot within the 128B row

  for (int kt = 0; kt < K; kt += 64) {
    __syncthreads();
#pragma unroll
    for (int i = 0; i < 4; ++i) {
      const int rr = (w * 4 + i) * 8 + rsub;       // tile row 0..127
      const int cA = cslot ^ (rr & 7);             // swizzled source 16B block
      async16(A + (size_t)(m0 + rr) * K + kt + cA * 8, As + (w * 4 + i) * 512, lane);
      async16(Bt + (size_t)(n0 + rr) * K + kt + cA * 8, Bs + (w * 4 + i) * 512, lane);
    }
    __syncthreads();
    const int am0 = wm + lc, am1 = wm + 32 + lc;
    const int bn0 = wn + lc, bn1 = wn + 32 + lc;
#pragma unroll
    for (int s = 0; s < 4; ++s) {
      const int c = s * 2 + hh;
      bf16x8 a0 = *(const bf16x8*)(As + am0 * 64 + ((c ^ (am0 & 7)) * 8));
      bf16x8 a1 = *(const bf16x8*)(As + am1 * 64 + ((c ^ (am1 & 7)) * 8));
      bf16x8 b0 = *(const bf16x8*)(Bs + bn0 * 64 + ((c ^ (bn0 & 7)) * 8));
      bf16x8 b1 = *(const bf16x8*)(Bs + bn1 * 64 + ((c ^ (bn1 & 7)) * 8));
      acc[0][0] = MFMA32(a0, b0, acc[0][0]);
      acc[0][1] = MFMA32(a0, b1, acc[0][1]);
      acc[1][0] = MFMA32(a1, b0, acc[1][0]);
      acc[1][1] = MFMA32(a1, b1, acc[1][1]);
    }
  }

  // ---- epilogue. C/D layout: col = lc, row = (r&3) + 8*(r>>2) + 4*hh ----
  if constexpr (EPI == 2) {
#pragma unroll
    for (int mt = 0; mt < 2; ++mt)
#pragma unroll
      for (int nt = 0; nt < 2; ++nt)
#pragma unroll
        for (int r = 0; r < 16; ++r) {
          int grow = m0 + wm + mt * 32 + (r & 3) + 8 * (r >> 2) + 4 * hh;
          int gcol = n0 + wn + nt * 32 + lc;
          oF[(size_t)grow * 1024 + gcol] = acc[mt][nt][r];
        }
  } else {
    const bool kstyle = (EPI == 1) || (blockIdx.x < 8);
    if (kstyle) {
      constexpr int SEQ = (EPI == 1) ? 64 : 4160;
      constexpr float SC = (EPI == 1) ? 0.125f : 1.0f;
#pragma unroll
      for (int mt = 0; mt < 2; ++mt)
#pragma unroll
        for (int nt = 0; nt < 2; ++nt)
#pragma unroll
          for (int r = 0; r < 16; ++r) {
            int grow = m0 + wm + mt * 32 + (r & 3) + 8 * (r >> 2) + 4 * hh;
            int gcol = n0 + wn + nt * 32 + lc;
            int bb = grow / SEQ, rr2 = grow - bb * SEQ;
            int h = gcol >> 6, d = gcol & 63;
            oK[(((size_t)(bb * 16 + h)) * SEQ + rr2) * 64 + d] = f2bf(acc[mt][nt][r] * SC);
          }
    } else {
      // V^T: transpose 128x128 tile through LDS, write coalesced rows of Vt(b,h,d,key)
      __syncthreads();
      u16* T = lds;  // [128 n][144 m] bf16
#pragma unroll
      for (int mt = 0; mt < 2; ++mt)
#pragma unroll
        for (int nt = 0; nt < 2; ++nt) {
          int nl = wn + nt * 32 + lc;
#pragma unroll
          for (int r4 = 0; r4 < 4; ++r4) {
            int ml = wm + mt * 32 + 8 * r4 + 4 * hh;
            ushort4 pk;
            pk.x = f2bf(acc[mt][nt][4 * r4 + 0]);
            pk.y = f2bf(acc[mt][nt][4 * r4 + 1]);
            pk.z = f2bf(acc[mt][nt][4 * r4 + 2]);
            pk.w = f2bf(acc[mt][nt][4 * r4 + 3]);
            *(ushort4*)(T + nl * 144 + ml) = pk;
          }
        }
      __syncthreads();
#pragma unroll
      for (int rr2 = 0; rr2 < 8; ++rr2) {
        int sig = tid + rr2 * 256;
        int n = sig >> 4, cm = (sig & 15) << 3;
        uint4 v = *(const uint4*)(T + n * 144 + cm);
        int gcol = n0 + n - 1024;            // V half: cols 1024..2047
        int h = gcol >> 6, d = gcol & 63;
        int grow = m0 + cm;
        int bb = grow / 4160, key = grow - bb * 4160;
        *(uint4*)(oV + (((size_t)(bb * 16 + h)) * 64 + d) * 4160 + key) = v;
      }
    }
  }
}

// ---------------- fused attention ------------------------------------------
// block = (b,h,split4). 4 waves, each owns a strided set of 64-key supertiles.
// S^T = K.Q^T (both straight from global as MFMA frags), exp (no max needed:
// logits bounded, mask bias -100 underflows), P -> per-wave swizzled LDS,
// O += P.V^T (Vt rows straight from global). Partial num/den to workspace.
__global__ void __launch_bounds__(256) attn_kernel(
    const u16* __restrict__ Q, const u16* __restrict__ Kb,
    const u16* __restrict__ Vt, const float* __restrict__ mask,
    float* __restrict__ nums, float* __restrict__ dens) {
  __shared__ __align__(16) u16 Ps[16384];  // 4 waves x [64 q][64 k] swizzled
  __shared__ float Osum[4160];             // [64 q][65] padded
  __shared__ float den_s[256];
  const int p = blockIdx.x;
  const int bh = p >> 2, s = p & 3;
  const int b = bh >> 4;
  const int tid = threadIdx.x, lane = tid & 63, w = tid >> 6;
  const int hh = lane >> 5, lc = lane & 31;

  for (int i = tid; i < 4160; i += 256) Osum[i] = 0.f;
  den_s[tid] = 0.f;
  __syncthreads();

  const u16* Qb = Q + (size_t)bh * 4096;
  const u16* Kbb = Kb + (size_t)bh * 266240;  // 4160*64
  const u16* Vtb = Vt + (size_t)bh * 266240;  // 64*4160

  bf16x8 qf[2][4];  // B-operand frags of Q (lane = q col)
#pragma unroll
  for (int qt = 0; qt < 2; ++qt)
#pragma unroll
    for (int ks = 0; ks < 4; ++ks)
      qf[qt][ks] = *(const bf16x8*)(Qb + (qt * 32 + lc) * 64 + ks * 16 + hh * 8);

  f32x16 o[2][2];
#pragma unroll
  for (int i = 0; i < 2; ++i)
#pragma unroll
    for (int j = 0; j < 2; ++j) o[i][j] = zero16();
  float den0 = 0.f, den1 = 0.f;
  u16* Pw = Ps + w * 4096;
  const int t0 = (s == 0) ? 0 : (16 * s + 1);          // splits: 17,16,16,16 supertiles
  const int t1 = (s == 3) ? 65 : (16 * (s + 1) + 1);

  for (int t = t0 + w; t < t1; t += 4) {
    const int key0 = t * 64;
    const int keyl = key0 + lane;
    float bias_v = 0.f;  // latent keys (>=4096): bias 0
    if (keyl < 4096) bias_v = (mask[b * 4096 + keyl] - 1.f) * 100.f;

    bf16x8 kf[2][4];  // A-operand frags of K (lane = key row)
#pragma unroll
    for (int ktt = 0; ktt < 2; ++ktt)
#pragma unroll
      for (int ks = 0; ks < 4; ++ks)
        kf[ktt][ks] = *(const bf16x8*)(Kbb + (size_t)(key0 + ktt * 32 + lc) * 64 + ks * 16 + hh * 8);

    f32x16 st[2][2];  // S^T tiles [key-tile][q-tile]; C rows = keys, cols = q
#pragma unroll
    for (int i = 0; i < 2; ++i)
#pragma unroll
      for (int j = 0; j < 2; ++j) st[i][j] = zero16();
#pragma unroll
    for (int ks = 0; ks < 4; ++ks) {
      st[0][0] = MFMA32(kf[0][ks], qf[0][ks], st[0][0]);
      st[0][1] = MFMA32(kf[0][ks], qf[1][ks], st[0][1]);
      st[1][0] = MFMA32(kf[1][ks], qf[0][ks], st[1][0]);
      st[1][1] = MFMA32(kf[1][ks], qf[1][ks], st[1][1]);
    }

#pragma unroll
    for (int ktt = 0; ktt < 2; ++ktt) {
      float bb[16];  // bias by key-row, broadcast from lane-keyed load
#pragma unroll
      for (int r = 0; r < 16; ++r)
        bb[r] = __shfl(bias_v, ktt * 32 + (r & 3) + 8 * (r >> 2) + 4 * hh);
#pragma unroll
      for (int qt = 0; qt < 2; ++qt) {
        const int q = qt * 32 + lc;
        float dsum = 0.f;
#pragma unroll
        for (int r4 = 0; r4 < 4; ++r4) {
          float e0 = __expf(st[ktt][qt][4 * r4 + 0] + bb[4 * r4 + 0]);
          float e1 = __expf(st[ktt][qt][4 * r4 + 1] + bb[4 * r4 + 1]);
          float e2 = __expf(st[ktt][qt][4 * r4 + 2] + bb[4 * r4 + 2]);
          float e3 = __expf(st[ktt][qt][4 * r4 + 3] + bb[4 * r4 + 3]);
          dsum += e0 + e1 + e2 + e3;
          ushort4 pk;
          pk.x = f2bf(e0); pk.y = f2bf(e1); pk.z = f2bf(e2); pk.w = f2bf(e3);
          const int c = ktt * 4 + r4;  // 16B block index along keys
          *(ushort4*)(Pw + q * 64 + ((c ^ (q & 7)) * 8) + 4 * hh) = pk;
        }
        if (qt == 0) den0 += dsum; else den1 += dsum;
      }
    }

    // O += P . V^T  (A = P rows from LDS, B = Vt rows from global)
#pragma unroll
    for (int ks = 0; ks < 4; ++ks) {
      const int c = ks * 2 + hh;
      bf16x8 p0 = *(const bf16x8*)(Pw + lc * 64 + ((c ^ (lc & 7)) * 8));
      bf16x8 p1 = *(const bf16x8*)(Pw + (32 + lc) * 64 + ((c ^ (lc & 7)) * 8));
      bf16x8 v0 = *(const bf16x8*)(Vtb + (size_t)lc * 4160 + key0 + ks * 16 + hh * 8);
      bf16x8 v1 = *(const bf16x8*)(Vtb + (size_t)(32 + lc) * 4160 + key0 + ks * 16 + hh * 8);
      o[0][0] = MFMA32(p0, v0, o[0][0]);
      o[0][1] = MFMA32(p0, v1, o[0][1]);
      o[1][0] = MFMA32(p1, v0, o[1][0]);
      o[1][1] = MFMA32(p1, v1, o[1][1]);
    }
  }

#pragma unroll
  for (int qt = 0; qt < 2; ++qt)
#pragma unroll
    for (int dt = 0; dt < 2; ++dt)
#pragma unroll
      for (int r = 0; r < 16; ++r) {
        int row = qt * 32 + (r & 3) + 8 * (r >> 2) + 4 * hh;
        int col = dt * 32 + lc;
        atomicAdd(&Osum[row * 65 + col], o[qt][dt][r]);
      }
  den0 += __shfl_xor(den0, 32);
  den1 += __shfl_xor(den1, 32);
  if (lane < 32) {
    den_s[w * 64 + lc] = den0;
    den_s[w * 64 + 32 + lc] = den1;
  }
  __syncthreads();
  float* np_ = nums + (size_t)p * 4096;
  for (int i = tid; i < 4096; i += 256)
    np_[i] = Osum[(i >> 6) * 65 + (i & 63)];
  if (tid < 64)
    dens[p * 64 + tid] = den_s[tid] + den_s[64 + tid] + den_s[128 + tid] + den_s[192 + tid];
}

// ---------------- combine split partials, write O bf16 (b,q,h*64+d) ---------
__global__ void combine_kernel(const float* __restrict__ nums, const float* __restrict__ dens,
                               u16* __restrict__ O) {
  int idx = blockIdx.x * 256 + threadIdx.x;  // 524288 total
  int bh = idx >> 12;
  int q = (idx >> 6) & 63, d = idx & 63;
  float n = 0.f, dn = 0.f;
#pragma unroll
  for (int s = 0; s < 4; ++s) {
    n += nums[(size_t)(bh * 4 + s) * 4096 + q * 64 + d];
    dn += dens[(bh * 4 + s) * 64 + q];
  }
  int b = bh >> 4, h = bh & 15;
  O[((size_t)(b * 64 + q) * 16 + h) * 64 + d] = f2bf(n / dn);
}

// ---------------------------------------------------------------------------
extern "C" void kernel_launch(void* const* d_in, const int* in_sizes, int n_in,
                              void* d_out, int out_size, void* d_ws, size_t ws_size,
                              hipStream_t stream) {
  (void)in_sizes; (void)n_in; (void)out_size; (void)ws_size;
  const float* x    = (const float*)d_in[0];
  const float* lat  = (const float*)d_in[1];
  const float* mask = (const float*)d_in[2];
  const float* g1   = (const float*)d_in[3];
  const float* b1   = (const float*)d_in[4];
  const float* g2   = (const float*)d_in[5];
  const float* b2   = (const float*)d_in[6];
  const float* Wq   = (const float*)d_in[7];
  const float* Wkv  = (const float*)d_in[8];
  const float* Wout = (const float*)d_in[9];
  float* out = (float*)d_out;

  unsigned char* w = (unsigned char*)d_ws;
  u16* kvin = (u16*)w;   w += (size_t)33280 * 1024 * 2;  // LN([x;latents]) bf16
  u16* qin = (u16*)w;    w += (size_t)512 * 1024 * 2;    // LN(latents) compact
  u16* WqT = (u16*)w;    w += (size_t)1024 * 1024 * 2;
  u16* WkvT = (u16*)w;   w += (size_t)2048 * 1024 * 2;
  u16* WoutT = (u16*)w;  w += (size_t)1024 * 1024 * 2;
  u16* Kbuf = (u16*)w;   w += (size_t)33280 * 1024 * 2;  // (b,h,key,d)
  u16* Vtb = (u16*)w;    w += (size_t)33280 * 1024 * 2;  // (b,h,d,key)
  u16* Qbuf = (u16*)w;   w += (size_t)512 * 1024 * 2;    // (b,h,q,d), pre-scaled 1/8
  u16* Obuf = (u16*)w;   w += (size_t)512 * 1024 * 2;    // (b,q,h*64+d)
  float* nums = (float*)w; w += (size_t)512 * 4096 * 4;
  float* dens = (float*)w; w += (size_t)512 * 64 * 4;

  wtrans<<<dim3(32, 32), dim3(32, 8), 0, stream>>>(Wq, WqT, 1024, 1024);
  wtrans<<<dim3(64, 32), dim3(32, 8), 0, stream>>>(Wkv, WkvT, 1024, 2048);
  wtrans<<<dim3(32, 32), dim3(32, 8), 0, stream>>>(Wout, WoutT, 1024, 1024);
  ln_kernel<<<33280, 256, 0, stream>>>(x, lat, g1, b1, g2, b2, kvin, qin);
  gemm128<0><<<dim3(16, 260), 256, 0, stream>>>(kvin, WkvT, 1024, Kbuf, Vtb, nullptr);
  gemm128<1><<<dim3(8, 4), 256, 0, stream>>>(qin, WqT, 1024, Qbuf, nullptr, nullptr);
  attn_kernel<<<512, 256, 0, stream>>>(Qbuf, Kbuf, Vtb, mask, nums, dens);
  combine_kernel<<<2048, 256, 0, stream>>>(nums, dens, Obuf);
  gemm128<2><<<dim3(8, 4), 256, 0, stream>>>(Obuf, WoutT, 1024, nullptr, nullptr, out);
}

// Round 2
// 437.491 us; speedup vs baseline: 1.1453x; 1.1453x over previous
//
#include <hip/hip_runtime.h>
#include <cstdint>
#include <cstddef>

// PerceiverAttention on MI355X (gfx950).
// wtrans_all -> ln -> gemm<KV> -> gemm<partial Q> -> qreduce -> attn(coop) ->
// combine -> gemm<partial OUT> -> oreduce
// All matmuls: bf16 MFMA 32x32x16, fp32 accum. 128x128 tile, BK=64,
// global_load_lds width=16, XOR-swizzled LDS (conflict-minimal ds_read_b128).

typedef unsigned short u16;
typedef __bf16 bf16x8 __attribute__((ext_vector_type(8)));
typedef float f32x16 __attribute__((ext_vector_type(16)));

#define MFMA32(a, b, c) __builtin_amdgcn_mfma_f32_32x32x16_bf16((a), (b), (c), 0, 0, 0)

__device__ __forceinline__ u16 f2bf(float f) {  // RNE float->bf16
  unsigned u = __builtin_bit_cast(unsigned, f);
  u += 0x7FFFu + ((u >> 16) & 1u);
  return (u16)(u >> 16);
}

__device__ __forceinline__ f32x16 zero16() {
  f32x16 z;
#pragma unroll
  for (int i = 0; i < 16; ++i) z[i] = 0.f;
  return z;
}

#if defined(__has_builtin)
#if __has_builtin(__builtin_amdgcn_global_load_lds)
#define HAVE_GLDS 1
#endif
#endif

// Async global->LDS, 16 B/lane. LDS dest = wave-uniform base + lane*16;
// global source is per-lane.
__device__ __forceinline__ void async16(const u16* g, u16* lbase, int lane) {
#ifdef HAVE_GLDS
  typedef const __attribute__((address_space(1))) void* gp_t;
  typedef __attribute__((address_space(3))) void* lp_t;
  __builtin_amdgcn_global_load_lds((gp_t)g, (lp_t)lbase, 16, 0, 0);
#else
  *(uint4*)(lbase + lane * 8) = *(const uint4*)g;
#endif
}

// ---------------- weight transposes fp32 -> bf16 (one launch) ---------------
__global__ void wtrans_all(const float* __restrict__ Wq, const float* __restrict__ Wkv,
                           const float* __restrict__ Wout, u16* __restrict__ WqT,
                           u16* __restrict__ WkvT, u16* __restrict__ WoutT) {
  __shared__ float t[32][33];
  const int z = blockIdx.z;
  const float* W;
  u16* Wt;
  int N, nbase;
  if (z == 0) { W = Wq; Wt = WqT; N = 1024; nbase = 0; }
  else if (z == 3) { W = Wout; Wt = WoutT; N = 1024; nbase = 0; }
  else { W = Wkv; Wt = WkvT; N = 2048; nbase = (z - 1) * 1024; }
  int n0 = nbase + blockIdx.x * 32, k0 = blockIdx.y * 32;
  int tx = threadIdx.x, ty = threadIdx.y;  // 32 x 8
#pragma unroll
  for (int i = 0; i < 4; ++i)
    t[ty + 8 * i][tx] = W[(size_t)(k0 + ty + 8 * i) * N + n0 + tx];
  __syncthreads();
#pragma unroll
  for (int i = 0; i < 4; ++i)
    Wt[(size_t)(n0 + ty + 8 * i) * 1024 + k0 + tx] = f2bf(t[tx][ty + 8 * i]);
}

// ---------------- LayerNorm of x and latents -> bf16 ------------------------
__global__ void ln_kernel(const float* __restrict__ x, const float* __restrict__ lat,
                          const float* __restrict__ g1, const float* __restrict__ b1,
                          const float* __restrict__ g2, const float* __restrict__ b2,
                          u16* __restrict__ kvin, u16* __restrict__ qin) {
  int row = blockIdx.x;
  const float *src, *g, *bb;
  u16 *dst, *dst2 = nullptr;
  if (row < 32768) {
    int b = row >> 12, pos = row & 4095;
    src = x + (size_t)row * 1024;
    dst = kvin + (size_t)(b * 4160 + pos) * 1024;
    g = g1; bb = b1;
  } else {
    int i = row - 32768;
    int b = i >> 6, j = i & 63;
    src = lat + (size_t)i * 1024;
    dst = kvin + (size_t)(b * 4160 + 4096 + j) * 1024;
    dst2 = qin + (size_t)i * 1024;
    g = g2; bb = b2;
  }
  int t = threadIdx.x;
  float4 v = *(const float4*)(src + t * 4);
  float s = v.x + v.y + v.z + v.w;
  float ss = v.x * v.x + v.y * v.y + v.z * v.z + v.w * v.w;
#pragma unroll
  for (int off = 32; off; off >>= 1) {
    s += __shfl_xor(s, off);
    ss += __shfl_xor(ss, off);
  }
  __shared__ float red[8];
  int w = t >> 6;
  if ((t & 63) == 0) { red[w] = s; red[w + 4] = ss; }
  __syncthreads();
  s = red[0] + red[1] + red[2] + red[3];
  ss = red[4] + red[5] + red[6] + red[7];
  float mu = s * (1.f / 1024.f);
  float var = ss * (1.f / 1024.f) - mu * mu;
  float rstd = rsqrtf(var + 1e-5f);
  float4 gv = *(const float4*)(g + t * 4);
  float4 bv = *(const float4*)(bb + t * 4);
  ushort4 o;
  o.x = f2bf((v.x - mu) * rstd * gv.x + bv.x);
  o.y = f2bf((v.y - mu) * rstd * gv.y + bv.y);
  o.z = f2bf((v.z - mu) * rstd * gv.z + bv.z);
  o.w = f2bf((v.w - mu) * rstd * gv.w + bv.w);
  *(ushort4*)(dst + t * 4) = o;
  if (dst2) *(ushort4*)(dst2 + t * 4) = o;
}

// ---------------- 128x128 bf16 GEMM: C[m][n] = sum_k A[m][k]*Bt[n][k] --------
// K-stride fixed at 1024. blockIdx.z = split-K chunk (k0 = z*kLen).
// EPI 0: KV proj. nb<8 -> K scatter (b,h,key,d); nb>=8 -> V supertile-blocked
//        VB[bh][t][d][kk] via LDS transpose.
// EPI 2: fp32 row-major partial (N=1024) to oF + z*512*1024.
template <int EPI>
__global__ void __launch_bounds__(256, 2) gemm128(
    const u16* __restrict__ A, const u16* __restrict__ Bt, int kLen,
    u16* __restrict__ oK, u16* __restrict__ oV, float* __restrict__ oF) {
  __shared__ __align__(16) u16 lds[18432];  // As 8192 | Bs 8192; epilogue reuse
  u16* As = lds;
  u16* Bs = lds + 8192;
  const int tid = threadIdx.x;
  const int lane = tid & 63;
  const int w = tid >> 6;
  const int lc = lane & 31;
  const int hh = lane >> 5;
  const int m0 = blockIdx.y * 128;
  const int n0 = blockIdx.x * 128;
  const int wm = (w >> 1) * 64;
  const int wn = (w & 1) * 64;
  const int k0 = blockIdx.z * kLen;

  f32x16 acc[2][2];
#pragma unroll
  for (int i = 0; i < 2; ++i)
#pragma unroll
    for (int j = 0; j < 2; ++j) acc[i][j] = zero16();

  const int rsub = lane >> 3;   // 0..7 : sub-row within a wave's 8-row chunk
  const int cslot = lane & 7;   // 0..7 : 16B slot within the 128B row

  for (int kt = k0; kt < k0 + kLen; kt += 64) {
    __syncthreads();
#pragma unroll
    for (int i = 0; i < 4; ++i) {
      const int rr = (w * 4 + i) * 8 + rsub;       // tile row 0..127
      const int cA = cslot ^ (rr & 7);             // swizzled source 16B block
      async16(A + (size_t)(m0 + rr) * 1024 + kt + cA * 8, As + (w * 4 + i) * 512, lane);
      async16(Bt + (size_t)(n0 + rr) * 1024 + kt + cA * 8, Bs + (w * 4 + i) * 512, lane);
    }
    __syncthreads();
    const int am0 = wm + lc, am1 = wm + 32 + lc;
    const int bn0 = wn + lc, bn1 = wn + 32 + lc;
#pragma unroll
    for (int s = 0; s < 4; ++s) {
      const int c = s * 2 + hh;
      bf16x8 a0 = *(const bf16x8*)(As + am0 * 64 + ((c ^ (am0 & 7)) * 8));
      bf16x8 a1 = *(const bf16x8*)(As + am1 * 64 + ((c ^ (am1 & 7)) * 8));
      bf16x8 b0 = *(const bf16x8*)(Bs + bn0 * 64 + ((c ^ (bn0 & 7)) * 8));
      bf16x8 b1 = *(const bf16x8*)(Bs + bn1 * 64 + ((c ^ (bn1 & 7)) * 8));
      acc[0][0] = MFMA32(a0, b0, acc[0][0]);
      acc[0][1] = MFMA32(a0, b1, acc[0][1]);
      acc[1][0] = MFMA32(a1, b0, acc[1][0]);
      acc[1][1] = MFMA32(a1, b1, acc[1][1]);
    }
  }

  // ---- epilogue. C/D layout: col = lc, row = (r&3) + 8*(r>>2) + 4*hh ----
  if constexpr (EPI == 2) {
    oF += (size_t)blockIdx.z * (512 * 1024);
#pragma unroll
    for (int mt = 0; mt < 2; ++mt)
#pragma unroll
      for (int nt = 0; nt < 2; ++nt)
#pragma unroll
        for (int r = 0; r < 16; ++r) {
          int grow = m0 + wm + mt * 32 + (r & 3) + 8 * (r >> 2) + 4 * hh;
          int gcol = n0 + wn + nt * 32 + lc;
          oF[(size_t)grow * 1024 + gcol] = acc[mt][nt][r];
        }
  } else {
    if (blockIdx.x < 8) {  // K half -> (b,h,key,d)
#pragma unroll
      for (int mt = 0; mt < 2; ++mt)
#pragma unroll
        for (int nt = 0; nt < 2; ++nt)
#pragma unroll
          for (int r = 0; r < 16; ++r) {
            int grow = m0 + wm + mt * 32 + (r & 3) + 8 * (r >> 2) + 4 * hh;
            int gcol = n0 + wn + nt * 32 + lc;
            int bb = grow / 4160, rr2 = grow - bb * 4160;
            int h = gcol >> 6, d = gcol & 63;
            oK[(((size_t)(bb * 16 + h)) * 4160 + rr2) * 64 + d] = f2bf(acc[mt][nt][r]);
          }
    } else {
      // V half: transpose via LDS, write supertile-blocked VB[bh][t][d][kk]
      __syncthreads();
      u16* T = lds;  // [128 n][144 m] bf16
#pragma unroll
      for (int mt = 0; mt < 2; ++mt)
#pragma unroll
        for (int nt = 0; nt < 2; ++nt) {
          int nl = wn + nt * 32 + lc;
#pragma unroll
          for (int r4 = 0; r4 < 4; ++r4) {
            int ml = wm + mt * 32 + 8 * r4 + 4 * hh;
            ushort4 pk;
            pk.x = f2bf(acc[mt][nt][4 * r4 + 0]);
            pk.y = f2bf(acc[mt][nt][4 * r4 + 1]);
            pk.z = f2bf(acc[mt][nt][4 * r4 + 2]);
            pk.w = f2bf(acc[mt][nt][4 * r4 + 3]);
            *(ushort4*)(T + nl * 144 + ml) = pk;
          }
        }
      __syncthreads();
#pragma unroll
      for (int rr2 = 0; rr2 < 8; ++rr2) {
        int sig = tid + rr2 * 256;
        int n = sig >> 4, cm = (sig & 15) << 3;
        uint4 v = *(const uint4*)(T + n * 144 + cm);
        int gcol = n0 + n - 1024;            // V half: cols 1024..2047
        int h = gcol >> 6, d = gcol & 63;
        int grow = m0 + cm;
        int bb = grow / 4160, key = grow - bb * 4160;
        int tt = key >> 6, kk = key & 63;
        *(uint4*)(oV + ((((size_t)(bb * 16 + h) * 65 + tt) * 64 + d) * 64 + kk)) = v;
      }
    }
  }
}

// ---------------- split-K reduce kernels ------------------------------------
__global__ void qreduce(const float* __restrict__ P, u16* __restrict__ Qbuf) {
  int idx = blockIdx.x * 256 + threadIdx.x;  // 524288
  float s = P[idx] + P[idx + 524288] + P[idx + 2 * 524288] + P[idx + 3 * 524288];
  int row = idx >> 10, col = idx & 1023;     // row=(b*64+q), col=(h*64+d)
  int b = row >> 6, q = row & 63, h = col >> 6, d = col & 63;
  Qbuf[((size_t)(b * 16 + h) * 64 + q) * 64 + d] = f2bf(s * 0.125f);
}

__global__ void oreduce(const float* __restrict__ P, float* __restrict__ out) {
  int idx = blockIdx.x * 256 + threadIdx.x;  // 524288
  out[idx] = P[idx] + P[idx + 524288] + P[idx + 2 * 524288] + P[idx + 3 * 524288];
}

// ---------------- fused attention (cooperative supertiles) ------------------
// block = (b,h,split4), 4 waves. Per 64-key supertile: all waves cooperatively
// stage K(64x64) + V(64d x 64k) (each 8 KB contiguous) via global_load_lds,
// double-buffered. S^T = K.Q^T (wave w: key-half w>>1, q-half w&1), exp,
// P -> shared swizzled LDS, barrier, O(q-half w>>1, d-half w&1) += P.V^T in
// registers. Partial num/den to workspace.
__global__ void __launch_bounds__(256) attn_kernel(
    const u16* __restrict__ Q, const u16* __restrict__ Kb,
    const u16* __restrict__ VB, const float* __restrict__ mask,
    float* __restrict__ nums, float* __restrict__ dens) {
  __shared__ __align__(16) u16 KT[2][4096];
  __shared__ __align__(16) u16 VT[2][4096];
  __shared__ __align__(16) u16 PT[4096];
  __shared__ float den_s[128];
  const int p = blockIdx.x;
  const int bh = p >> 2, s = p & 3;
  const int b = bh >> 4;
  const int tid = threadIdx.x, lane = tid & 63, w = tid >> 6;
  const int hh = lane >> 5, lc = lane & 31;
  const int rsub = lane >> 3, cslot = lane & 7;
  const int kh = w >> 1, qh = w & 1;    // S^T tile ownership
  const int qh2 = w >> 1, dh2 = w & 1;  // O tile ownership

  const u16* Qb = Q + (size_t)bh * 4096;
  const u16* Kbb = Kb + (size_t)bh * 266240;   // 4160*64
  const u16* Vbb = VB + (size_t)bh * 266240;   // 65*64*64

  bf16x8 qf[4];  // persistent Q B-frags for this wave's q-half
#pragma unroll
  for (int ks = 0; ks < 4; ++ks)
    qf[ks] = *(const bf16x8*)(Qb + (qh * 32 + lc) * 64 + ks * 16 + hh * 8);

  f32x16 o = zero16();
  float den_reg = 0.f;
  const int t0 = (s == 0) ? 0 : (16 * s + 1);  // splits: 17,16,16,16 supertiles
  const int t1 = (s == 3) ? 65 : (16 * s + 17);

  auto stage = [&](int t, int buf) {
    const u16* ksrc = Kbb + (size_t)t * 4096;
    const u16* vsrc = Vbb + (size_t)t * 4096;
    const int soff = rsub * 64 + ((cslot ^ rsub) * 8);
#pragma unroll
    for (int i = 0; i < 2; ++i) {
      const int c = w * 2 + i;  // chunk 0..7 (8 rows each)
      async16(ksrc + c * 512 + soff, KT[buf] + c * 512, lane);
      async16(vsrc + c * 512 + soff, VT[buf] + c * 512, lane);
    }
  };

  stage(t0, 0);
  for (int t = t0; t < t1; ++t) {
    const int buf = (t - t0) & 1;
    __syncthreads();  // barrier A: stage(t) drained by each wave
    if (t + 1 < t1) stage(t + 1, buf ^ 1);

    // bias for this wave's 32 key rows (lane lc holds key kh*32+lc)
    float bias_v = 0.f;
    {
      int key_l = t * 64 + kh * 32 + lc;
      if (key_l < 4096) bias_v = (mask[b * 4096 + key_l] - 1.f) * 100.f;
    }

    // S^T tile (keys kh-half x q qh-half)
    f32x16 st = zero16();
    const int R = kh * 32 + lc;
#pragma unroll
    for (int ks = 0; ks < 4; ++ks) {
      const int c = ks * 2 + hh;
      bf16x8 kfr = *(const bf16x8*)(KT[buf] + R * 64 + ((c ^ (R & 7)) * 8));
      st = MFMA32(kfr, qf[ks], st);
    }

    // exp + P write (P[q][key] swizzled for A-frag reads)
    const int q = qh * 32 + lc;
    float dsum = 0.f;
#pragma unroll
    for (int r4 = 0; r4 < 4; ++r4) {
      float bb0 = __shfl(bias_v, 0 + 8 * r4 + 4 * hh);
      float bb1 = __shfl(bias_v, 1 + 8 * r4 + 4 * hh);
      float bb2 = __shfl(bias_v, 2 + 8 * r4 + 4 * hh);
      float bb3 = __shfl(bias_v, 3 + 8 * r4 + 4 * hh);
      float e0 = __expf(st[4 * r4 + 0] + bb0);
      float e1 = __expf(st[4 * r4 + 1] + bb1);
      float e2 = __expf(st[4 * r4 + 2] + bb2);
      float e3 = __expf(st[4 * r4 + 3] + bb3);
      dsum += e0 + e1 + e2 + e3;
      ushort4 pk;
      pk.x = f2bf(e0); pk.y = f2bf(e1); pk.z = f2bf(e2); pk.w = f2bf(e3);
      const int cblk = kh * 4 + r4;
      *(ushort4*)(PT + q * 64 + ((cblk ^ (q & 7)) * 8) + 4 * hh) = pk;
    }
    den_reg += dsum;
    __syncthreads();  // barrier B: PT complete

    // O(qh2, dh2) += P . V^T
    const int qr = qh2 * 32 + lc;
    const int dr = dh2 * 32 + lc;
#pragma unroll
    for (int ks = 0; ks < 4; ++ks) {
      const int c = ks * 2 + hh;
      bf16x8 pf = *(const bf16x8*)(PT + qr * 64 + ((c ^ (qr & 7)) * 8));
      bf16x8 vf = *(const bf16x8*)(VT[buf] + dr * 64 + ((c ^ (dr & 7)) * 8));
      o = MFMA32(pf, vf, o);
    }
  }

  // write partial nums (fp32) and dens
  float* np_ = nums + (size_t)p * 4096;
#pragma unroll
  for (int r = 0; r < 16; ++r) {
    int row = qh2 * 32 + (r & 3) + 8 * (r >> 2) + 4 * hh;
    np_[row * 64 + dh2 * 32 + lc] = o[r];
  }
  den_reg += __shfl_xor(den_reg, 32);
  if (lane < 32) den_s[w * 32 + lc] = den_reg;
  __syncthreads();
  if (tid < 64) {
    int g = tid >> 5, l = tid & 31;
    dens[p * 64 + tid] = den_s[g * 32 + l] + den_s[(g + 2) * 32 + l];
  }
}

// ---------------- combine split partials, write O bf16 (b,q,h*64+d) ---------
__global__ void combine_kernel(const float* __restrict__ nums, const float* __restrict__ dens,
                               u16* __restrict__ O) {
  int idx = blockIdx.x * 256 + threadIdx.x;  // 524288 total
  int bh = idx >> 12;
  int q = (idx >> 6) & 63, d = idx & 63;
  float n = 0.f, dn = 0.f;
#pragma unroll
  for (int s = 0; s < 4; ++s) {
    n += nums[(size_t)(bh * 4 + s) * 4096 + q * 64 + d];
    dn += dens[(bh * 4 + s) * 64 + q];
  }
  int b = bh >> 4, h = bh & 15;
  O[((size_t)(b * 64 + q) * 16 + h) * 64 + d] = f2bf(n / dn);
}

// ---------------------------------------------------------------------------
extern "C" void kernel_launch(void* const* d_in, const int* in_sizes, int n_in,
                              void* d_out, int out_size, void* d_ws, size_t ws_size,
                              hipStream_t stream) {
  (void)in_sizes; (void)n_in; (void)out_size; (void)ws_size;
  const float* x    = (const float*)d_in[0];
  const float* lat  = (const float*)d_in[1];
  const float* mask = (const float*)d_in[2];
  const float* g1   = (const float*)d_in[3];
  const float* b1   = (const float*)d_in[4];
  const float* g2   = (const float*)d_in[5];
  const float* b2   = (const float*)d_in[6];
  const float* Wq   = (const float*)d_in[7];
  const float* Wkv  = (const float*)d_in[8];
  const float* Wout = (const float*)d_in[9];
  float* out = (float*)d_out;

  unsigned char* w = (unsigned char*)d_ws;
  u16* kvin = (u16*)w;   w += (size_t)33280 * 1024 * 2;  // LN([x;latents]) bf16
  u16* qin = (u16*)w;    w += (size_t)512 * 1024 * 2;    // LN(latents) compact
  u16* WqT = (u16*)w;    w += (size_t)1024 * 1024 * 2;
  u16* WkvT = (u16*)w;   w += (size_t)2048 * 1024 * 2;
  u16* WoutT = (u16*)w;  w += (size_t)1024 * 1024 * 2;
  u16* Kbuf = (u16*)w;   w += (size_t)33280 * 1024 * 2;  // (b,h,key,d)
  u16* Vbuf = (u16*)w;   w += (size_t)33280 * 1024 * 2;  // (b,h,t,d,kk) blocked
  u16* Qbuf = (u16*)w;   w += (size_t)512 * 1024 * 2;    // (b,h,q,d), pre-scaled 1/8
  u16* Obuf = (u16*)w;   w += (size_t)512 * 1024 * 2;    // (b,q,h*64+d)
  float* part = (float*)w; w += (size_t)4 * 512 * 1024 * 4;  // split-K partials
  float* nums = (float*)w; w += (size_t)512 * 4096 * 4;
  float* dens = (float*)w; w += (size_t)512 * 64 * 4;

  wtrans_all<<<dim3(32, 32, 4), dim3(32, 8), 0, stream>>>(Wq, Wkv, Wout, WqT, WkvT, WoutT);
  ln_kernel<<<33280, 256, 0, stream>>>(x, lat, g1, b1, g2, b2, kvin, qin);
  gemm128<0><<<dim3(16, 260, 1), 256, 0, stream>>>(kvin, WkvT, 1024, Kbuf, Vbuf, nullptr);
  gemm128<2><<<dim3(8, 4, 4), 256, 0, stream>>>(qin, WqT, 256, nullptr, nullptr, part);
  qreduce<<<2048, 256, 0, stream>>>(part, Qbuf);
  attn_kernel<<<512, 256, 0, stream>>>(Qbuf, Kbuf, Vbuf, mask, nums, dens);
  combine_kernel<<<2048, 256, 0, stream>>>(nums, dens, Obuf);
  gemm128<2><<<dim3(8, 4, 4), 256, 0, stream>>>(Obuf, WoutT, 256, nullptr, nullptr, part);
  oreduce<<<2048, 256, 0, stream>>>(part, out);
}